// Round 5
// baseline (83.580 us; speedup 1.0000x reference)
//
#include <hip/hip_runtime.h>
#include <math.h>

#define N0 200000
#define N1 1024
#define N2 256
#define N3 32
#define NE0 2048000
#define NE1 262144
#define NE2 8192
#define BATCH 32
#define NCLS 10
#define SPLIT0 2   // sub-blocks per dst segment in gather0

typedef _Float16 h2 __attribute__((ext_vector_type(2)));
typedef _Float16 h8 __attribute__((ext_vector_type(8)));

__device__ __forceinline__ int lower_bound_i(const int* __restrict__ a, int n, int key) {
    int lo = 0, hi = n;
    while (lo < hi) {
        int mid = (lo + hi) >> 1;
        if (a[mid] < key) lo = mid + 1; else hi = mid;
    }
    return lo;
}

// x (32, 200000) fp32 -> xt (200000, 32) fp16 rows (64 B each), LDS tiled.
__global__ __launch_bounds__(256) void k_transpose(const float* __restrict__ x,
                                                   h2* __restrict__ xt) {
    __shared__ float tile[32][65];
    const int col0 = blockIdx.x * 64;
    const int tid = threadIdx.x;
    const int c = tid & 63, r0 = tid >> 6;       // 4 row-lanes
    #pragma unroll
    for (int r = r0; r < 32; r += 4) {
        int col = col0 + c;
        tile[r][c] = (col < N0) ? x[r * N0 + col] : 0.f;
    }
    __syncthreads();
    const int bb = (tid & 15) * 2, c0 = tid >> 4; // 16 col-lanes, 2 batch rows/thread
    #pragma unroll
    for (int cc = c0; cc < 64; cc += 16) {
        int col = col0 + cc;
        if (col < N0) {
            h2 v;
            v[0] = (_Float16)tile[bb][cc];
            v[1] = (_Float16)tile[bb + 1][cc];
            xt[col * 16 + (bb >> 1)] = v;
        }
    }
}

// Layer-0 gather, segment-split for occupancy: block (n, c) handles the c-th
// 1/SPLIT0 slice of dst-segment n, writing fp32 partial rows.
// grid = N1 * SPLIT0 blocks; partials reduced by k_reduce.
__global__ __launch_bounds__(256) void k_gather0(const h8* __restrict__ table,
                                                 const int* __restrict__ src,
                                                 const int* __restrict__ dst,
                                                 float* __restrict__ out_part) {
    const int n = blockIdx.x >> 1;
    const int c = blockIdx.x & (SPLIT0 - 1);
    const int e0 = lower_bound_i(dst, NE0, n);
    const int e1 = lower_bound_i(dst, NE0, n + 1);
    const int len = e1 - e0;
    const int q0 = e0 + (len * c) / SPLIT0;
    const int q1 = e0 + (len * (c + 1)) / SPLIT0;
    const int tid = threadIdx.x;
    const int b4 = tid & 3;       // which 16B chunk of the 64B row
    const int g  = tid >> 2;      // 64 edge groups
    float acc[8] = {0.f, 0.f, 0.f, 0.f, 0.f, 0.f, 0.f, 0.f};
    int e = q0 + g;
    for (; e + 192 < q1; e += 256) {
        int s0 = __builtin_nontemporal_load(src + e);
        int s1 = __builtin_nontemporal_load(src + e + 64);
        int s2 = __builtin_nontemporal_load(src + e + 128);
        int s3 = __builtin_nontemporal_load(src + e + 192);
        h8 v0 = table[s0 * 4 + b4];
        h8 v1 = table[s1 * 4 + b4];
        h8 v2 = table[s2 * 4 + b4];
        h8 v3 = table[s3 * 4 + b4];
        #pragma unroll
        for (int i = 0; i < 8; ++i)
            acc[i] += (float)v0[i] + (float)v1[i] + (float)v2[i] + (float)v3[i];
    }
    for (; e < q1; e += 64) {
        int s = __builtin_nontemporal_load(src + e);
        h8 v = table[s * 4 + b4];
        #pragma unroll
        for (int i = 0; i < 8; ++i) acc[i] += (float)v[i];
    }
    __shared__ float red[64][33];
    #pragma unroll
    for (int i = 0; i < 8; ++i) red[g][b4 * 8 + i] = acc[i];
    __syncthreads();
    #pragma unroll
    for (int s = 32; s >= 1; s >>= 1) {
        if (g < s) {
            #pragma unroll
            for (int i = 0; i < 8; ++i)
                red[g][b4 * 8 + i] += red[g + s][b4 * 8 + i];
        }
        __syncthreads();
    }
    if (tid < 32) out_part[(c * N1 + n) * 32 + tid] = red[0][tid];
}

// Sum SPLIT0 partials -> fp16 table for the next gather.
__global__ __launch_bounds__(256) void k_reduce(const float* __restrict__ part,
                                                _Float16* __restrict__ out) {
    int i = blockIdx.x * 256 + threadIdx.x;   // [0, N1*32)
    float s = part[i] + part[N1 * 32 + i];
    out[i] = (_Float16)s;
}

// Segmented gather-sum over fp16 rows (layers 1-2).
__global__ __launch_bounds__(256) void k_gather(const h8* __restrict__ table,
                                                const int* __restrict__ src,
                                                const int* __restrict__ dst,
                                                int nedges,
                                                _Float16* __restrict__ out_h,
                                                float* __restrict__ out_f,
                                                const float* __restrict__ cnt_in,
                                                float* __restrict__ cnt_out,
                                                float* __restrict__ t_out) {
    const int n = blockIdx.x;
    const int e0 = lower_bound_i(dst, nedges, n);
    const int e1 = lower_bound_i(dst, nedges, n + 1);
    const int tid = threadIdx.x;
    const int b4 = tid & 3;
    const int g  = tid >> 2;
    float acc[8] = {0.f, 0.f, 0.f, 0.f, 0.f, 0.f, 0.f, 0.f};
    float tacc = 0.f;
    int e = e0 + g;
    for (; e + 192 < e1; e += 256) {
        int s0 = __builtin_nontemporal_load(src + e);
        int s1 = __builtin_nontemporal_load(src + e + 64);
        int s2 = __builtin_nontemporal_load(src + e + 128);
        int s3 = __builtin_nontemporal_load(src + e + 192);
        h8 v0 = table[s0 * 4 + b4];
        h8 v1 = table[s1 * 4 + b4];
        h8 v2 = table[s2 * 4 + b4];
        h8 v3 = table[s3 * 4 + b4];
        #pragma unroll
        for (int i = 0; i < 8; ++i)
            acc[i] += (float)v0[i] + (float)v1[i] + (float)v2[i] + (float)v3[i];
        if (cnt_in != nullptr && b4 == 0)
            tacc += cnt_in[s0] + cnt_in[s1] + cnt_in[s2] + cnt_in[s3];
    }
    for (; e < e1; e += 64) {
        int s = __builtin_nontemporal_load(src + e);
        h8 v = table[s * 4 + b4];
        #pragma unroll
        for (int i = 0; i < 8; ++i) acc[i] += (float)v[i];
        if (cnt_in != nullptr && b4 == 0) tacc += cnt_in[s];
    }
    __shared__ float red[64][33];
    __shared__ float tred[64];
    #pragma unroll
    for (int i = 0; i < 8; ++i) red[g][b4 * 8 + i] = acc[i];
    if (b4 == 0) tred[g] = tacc;
    __syncthreads();
    #pragma unroll
    for (int s = 32; s >= 1; s >>= 1) {
        if (g < s) {
            #pragma unroll
            for (int i = 0; i < 8; ++i)
                red[g][b4 * 8 + i] += red[g + s][b4 * 8 + i];
            if (b4 == 0) tred[g] += tred[g + s];
        }
        __syncthreads();
    }
    if (tid < 32) {
        float v = red[0][tid];
        if (out_h != nullptr) out_h[n * 32 + tid] = (_Float16)v;
        if (out_f != nullptr) out_f[n * 32 + tid] = v;
    } else if (tid == 32 && cnt_out != nullptr) {
        cnt_out[n] = (float)(e1 - e0);
    } else if (tid == 33 && t_out != nullptr) {
        t_out[n] = tred[0];
    }
}

// Weight algebra + final output. One block per class k (10 blocks, 256 threads).
__global__ __launch_bounds__(256) void k_out(
    const float* __restrict__ V0, const float* __restrict__ g0, const float* __restrict__ b0,
    const float* __restrict__ V1, const float* __restrict__ g1, const float* __restrict__ b1,
    const float* __restrict__ V2, const float* __restrict__ g2, const float* __restrict__ b2,
    const float* __restrict__ Vfc, const float* __restrict__ gfc, const float* __restrict__ bfc,
    const float* __restrict__ S2, const float* __restrict__ T2, const float* __restrict__ cnt2,
    float* __restrict__ out) {
    const int k = blockIdx.x;
    const int tid = threadIdx.x;
    __shared__ float w0[32], u[64], v[64], p[128], q[128], r[128];
    __shared__ float redA[8][32], redB[8][32], redC[8][32], redD[8][32];
    __shared__ float nnred[4];
    __shared__ float M[32];
    __shared__ float scale_s, Kc_s;

    if (tid < 32) {
        float val = V0[tid];
        w0[tid] = g0[tid] * val / fabsf(val);
    }
    __syncthreads();
    if (tid < 64) {
        float nn = 0.f;
        #pragma unroll
        for (int c = 0; c < 32; ++c) { float t = V1[tid * 32 + c]; nn += t * t; }
        float inv = g1[tid] * rsqrtf(nn);
        float su = 0.f, sv = 0.f;
        #pragma unroll
        for (int c = 0; c < 32; ++c) {
            float w = V1[tid * 32 + c] * inv;
            su += w * w0[c]; sv += w * b0[c];
        }
        u[tid] = su; v[tid] = sv;
    }
    __syncthreads();
    if (tid < 128) {
        float nn = 0.f;
        #pragma unroll
        for (int c = 0; c < 64; ++c) { float t = V2[tid * 64 + c]; nn += t * t; }
        float inv = g2[tid] * rsqrtf(nn);
        float sp = 0.f, sq = 0.f, sr = 0.f;
        #pragma unroll
        for (int c = 0; c < 64; ++c) {
            float w = V2[tid * 64 + c] * inv;
            sp += w * u[c]; sq += w * v[c]; sr += w * b1[c];
        }
        p[tid] = sp; q[tid] = sq; r[tid] = sr;
    }
    __syncthreads();

    const int n3 = tid & 31, og = tid >> 5;
    float nn = 0.f, mk = 0.f, mq = 0.f, mr = 0.f, mb = 0.f;
    #pragma unroll
    for (int i = 0; i < 16; ++i) {
        int o = og + 8 * i;
        float w = Vfc[k * 4096 + tid + 256 * i];
        nn += w * w;
        mk += w * p[o]; mq += w * q[o]; mr += w * r[o]; mb += w * b2[o];
    }
    #pragma unroll
    for (int off = 32; off; off >>= 1) nn += __shfl_xor(nn, off);
    if ((tid & 63) == 0) nnred[tid >> 6] = nn;
    redA[og][n3] = mk; redB[og][n3] = mq; redC[og][n3] = mr; redD[og][n3] = mb;
    __syncthreads();
    if (tid == 0) {
        float s = nnred[0] + nnred[1] + nnred[2] + nnred[3];
        scale_s = gfc[k] * rsqrtf(s);
    }
    __syncthreads();
    if (tid < 32) {
        float smk = 0.f, smq = 0.f, smr = 0.f, smb = 0.f;
        #pragma unroll
        for (int i = 0; i < 8; ++i) {
            smk += redA[i][tid]; smq += redB[i][tid];
            smr += redC[i][tid]; smb += redD[i][tid];
        }
        float scale = scale_s;
        M[tid] = scale * smk;
        float kcp = scale * (smq * T2[tid] + smr * cnt2[tid] + smb);
        #pragma unroll
        for (int off = 16; off; off >>= 1) kcp += __shfl_xor(kcp, off);
        if (tid == 0) Kc_s = kcp + bfc[k];
    }
    __syncthreads();
    if (tid < 32) {
        int b = tid;
        float s = 0.f;
        #pragma unroll
        for (int n = 0; n < 32; ++n) s += M[n] * S2[n * 32 + b];
        out[b * NCLS + k] = s + Kc_s;
    }
}

extern "C" void kernel_launch(void* const* d_in, const int* in_sizes, int n_in,
                              void* d_out, int out_size, void* d_ws, size_t ws_size,
                              hipStream_t stream) {
    const float* x   = (const float*)d_in[0];
    const int* src0  = (const int*)d_in[1];
    const int* dst0  = (const int*)d_in[2];
    const int* src1  = (const int*)d_in[3];
    const int* dst1  = (const int*)d_in[4];
    const int* src2  = (const int*)d_in[5];
    const int* dst2  = (const int*)d_in[6];
    const float* V0  = (const float*)d_in[7];
    const float* g0  = (const float*)d_in[8];
    const float* b0  = (const float*)d_in[9];
    const float* V1  = (const float*)d_in[10];
    const float* g1  = (const float*)d_in[11];
    const float* b1  = (const float*)d_in[12];
    const float* V2  = (const float*)d_in[13];
    const float* g2  = (const float*)d_in[14];
    const float* b2  = (const float*)d_in[15];
    const float* Vfc = (const float*)d_in[16];
    const float* gfc = (const float*)d_in[17];
    const float* bfc = (const float*)d_in[18];

    char* ws = (char*)d_ws;
    _Float16* xt  = (_Float16*)(ws);                 // 200000*32*2 = 12,800,000 B
    float* P0p    = (float*)(ws + 12800000);         // 2*1024*32*4 = 262,144 B
    _Float16* P0h = (_Float16*)(ws + 13062144);      // 1024*32*2   = 65,536 B
    _Float16* S1h = (_Float16*)(ws + 13127680);      // 256*32*2    = 16,384 B
    float* cnt1   = (float*)(ws + 13144064);         // 256*4       = 1,024 B
    float* S2     = (float*)(ws + 13145088);         // 32*32*4     = 4,096 B
    float* T2     = (float*)(ws + 13149184);         // 32*4        = 128 B
    float* cnt2   = (float*)(ws + 13149312);         // 32*4        = 128 B

    k_transpose<<<(N0 + 63) / 64, 256, 0, stream>>>(x, (h2*)xt);
    k_gather0<<<N1 * SPLIT0, 256, 0, stream>>>((const h8*)xt, src0, dst0, P0p);
    k_reduce<<<(N1 * 32) / 256, 256, 0, stream>>>(P0p, P0h);
    k_gather<<<N2, 256, 0, stream>>>((const h8*)P0h, src1, dst1, NE1,
                                     S1h, nullptr, nullptr, cnt1, nullptr);
    k_gather<<<N3, 256, 0, stream>>>((const h8*)S1h, src2, dst2, NE2,
                                     nullptr, S2, cnt1, cnt2, T2);
    k_out<<<NCLS, 256, 0, stream>>>(V0, g0, b0, V1, g1, b1, V2, g2, b2,
                                    Vfc, gfc, bfc, S2, T2, cnt2, (float*)d_out);
}